// Round 12
// baseline (295.561 us; speedup 1.0000x reference)
//
#include <hip/hip_runtime.h>
#include <math.h>

#define BB 4
#define SS 1024
#define DD 1024
#define HH 16
#define DKK 64
#define NN (BB*SS)          // 4096 rows
#define LN_EPS 1e-5f
#define JB 64

typedef __attribute__((ext_vector_type(8))) short bf16x8;
typedef __attribute__((ext_vector_type(4))) float f32x4;
typedef __attribute__((address_space(3))) unsigned int lds_u32;
typedef const __attribute__((address_space(1))) unsigned int glb_u32;

static __device__ __forceinline__ unsigned short f2bf(float x){
    unsigned int u = __float_as_uint(x);
    u += 0x7fff + ((u >> 16) & 1);     // round-to-nearest-even
    return (unsigned short)(u >> 16);
}

// ---------------------------------------------------------------------------
// all f32->bf16 conversions in one kernel. grid 8192:
// [0,6144): q/k/v (2048 each) -> xout slots; [6144,8192): wq/wk/wv/wo (512 each)
// ---------------------------------------------------------------------------
__global__ __launch_bounds__(256)
void k_cvt_all(const float* __restrict__ q, const float* __restrict__ k,
               const float* __restrict__ v, const float* __restrict__ w0,
               const float* __restrict__ w1, const float* __restrict__ w2,
               const float* __restrict__ w3, unsigned short* __restrict__ xout,
               unsigned short* __restrict__ wout){
    const int bidx = blockIdx.x;
    const float* src; unsigned short* dst; size_t i;
    if (bidx < 6144) {
        const int z = bidx >> 11, bi = bidx & 2047;
        src = (z == 0) ? q : (z == 1) ? k : v;
        dst = xout + (size_t)z*NN*DD;
        i = ((size_t)bi*256 + threadIdx.x)*8;
    } else {
        const int z = (bidx - 6144) >> 9, bi = (bidx - 6144) & 511;
        src = (z == 0) ? w0 : (z == 1) ? w1 : (z == 2) ? w2 : w3;
        dst = wout + (size_t)z*DD*DD;
        i = ((size_t)bi*256 + threadIdx.x)*8;
    }
    float4 a = *reinterpret_cast<const float4*>(&src[i]);
    float4 b = *reinterpret_cast<const float4*>(&src[i+4]);
    int4 w;
    w.x = (int)((unsigned)f2bf(a.x) | ((unsigned)f2bf(a.y) << 16));
    w.y = (int)((unsigned)f2bf(a.z) | ((unsigned)f2bf(a.w) << 16));
    w.z = (int)((unsigned)f2bf(b.x) | ((unsigned)f2bf(b.y) << 16));
    w.w = (int)((unsigned)f2bf(b.z) | ((unsigned)f2bf(b.w) << 16));
    *reinterpret_cast<int4*>(&dst[i]) = w;
}

// ---------------------------------------------------------------------------
// Unified QKV projection GEMM, grid (32, 8, 3).  z selects {Q,K,V}.
// z<2: bf16 out row-major (N,D).   z==2: bf16 out transposed (B,H,dk,S).
// ---------------------------------------------------------------------------
__global__ __launch_bounds__(256)
void k_gemmqkv(const unsigned short* __restrict__ Xb, const unsigned short* __restrict__ Wb,
               const float* __restrict__ b0, const float* __restrict__ b1,
               const float* __restrict__ b2, unsigned short* __restrict__ outb)
{
    __shared__ __align__(16) unsigned short Als[128*32];
    __shared__ __align__(16) unsigned short Bls[128*32];
    __shared__ __align__(16) unsigned short Cs[128*128];
    const int z = blockIdx.z;
    const unsigned short* X = Xb + (size_t)z*NN*DD;
    const unsigned short* W = Wb + (size_t)z*DD*DD;
    const float* bias = (z == 0) ? b0 : (z == 1) ? b1 : b2;
    unsigned short* out = outb + (size_t)z*NN*DD;

    const int row0 = blockIdx.x * 128;
    const int col0 = blockIdx.y * 128;
    const int t = threadIdx.x;
    const int w = t >> 6, l = t & 63;
    const int wr = w >> 1, wc = w & 1;

    f32x4 acc[4][4];
    #pragma unroll
    for (int m=0;m<4;++m)
        #pragma unroll
        for (int n=0;n<4;++n) acc[m][n] = (f32x4){0.f,0.f,0.f,0.f};

    const int srow  = l >> 2;
    const int skoff = (l & 3) * 8;

    for (int kt = 0; kt < DD; kt += 32) {
        #pragma unroll
        for (int i=0;i<2;++i) {
            const unsigned short* ga = X + (size_t)(row0 + w*32 + i*16 + srow)*DD + kt + skoff;
            const unsigned short* gb = W + (size_t)(col0 + w*32 + i*16 + srow)*DD + kt + skoff;
            __builtin_amdgcn_global_load_lds((glb_u32*)ga, (lds_u32*)&Als[(w*2+i)*512], 16, 0, 0);
            __builtin_amdgcn_global_load_lds((glb_u32*)gb, (lds_u32*)&Bls[(w*2+i)*512], 16, 0, 0);
        }
        __syncthreads();
        bf16x8 af[4], bfr[4];
        #pragma unroll
        for (int m=0;m<4;++m)
            af[m] = *reinterpret_cast<const bf16x8*>(&Als[(wr*64 + m*16 + (l&15))*32 + (l>>4)*8]);
        #pragma unroll
        for (int n=0;n<4;++n)
            bfr[n] = *reinterpret_cast<const bf16x8*>(&Bls[(wc*64 + n*16 + (l&15))*32 + (l>>4)*8]);
        __builtin_amdgcn_s_setprio(1);
        #pragma unroll
        for (int m=0;m<4;++m)
            #pragma unroll
            for (int n=0;n<4;++n)
                acc[m][n] = __builtin_amdgcn_mfma_f32_16x16x32_bf16(af[m], bfr[n], acc[m][n], 0, 0, 0);
        __builtin_amdgcn_s_setprio(0);
        __syncthreads();
    }

    if (z < 2) {
        #pragma unroll
        for (int m=0;m<4;++m){
            const int trb = wr*64 + m*16 + ((l>>4)<<2);
            #pragma unroll
            for (int n=0;n<4;++n){
                const int tc = wc*64 + n*16 + (l&15);
                const float bc = bias[col0 + tc];
                #pragma unroll
                for (int r=0;r<4;++r){
                    const int tr = trb + r;
                    *reinterpret_cast<unsigned short*>(
                        (char*)Cs + ((tr*256 + tc*2) ^ ((tr & 12) << 3))) = f2bf(acc[m][n][r] + bc);
                }
            }
        }
        __syncthreads();
        #pragma unroll
        for (int i=0;i<8;++i){
            const int slot = i*256 + t;
            const int r2 = slot >> 4, g = slot & 15;
            int4 v = *reinterpret_cast<const int4*>(
                (char*)Cs + ((r2*256 + g*16) ^ ((r2 & 12) << 3)));
            *reinterpret_cast<int4*>(&out[(size_t)(row0 + r2)*DD + col0 + g*8]) = v;
        }
    } else {
        #pragma unroll
        for (int m=0;m<4;++m){
            const int trb = wr*64 + m*16 + ((l>>4)<<2);
            #pragma unroll
            for (int n=0;n<4;++n){
                const int tc = wc*64 + n*16 + (l&15);
                const float bc = bias[col0 + tc];
                ushort4 pk;
                pk.x = f2bf(acc[m][n][0] + bc);
                pk.y = f2bf(acc[m][n][1] + bc);
                pk.z = f2bf(acc[m][n][2] + bc);
                pk.w = f2bf(acc[m][n][3] + bc);
                *reinterpret_cast<ushort4*>(
                    (char*)Cs + ((tc*256 + trb*2) ^ ((tc & 15) << 3))) = pk;
            }
        }
        __syncthreads();
        const int b = row0 >> 10;
        const int sbase = row0 & 1023;
        #pragma unroll
        for (int i=0;i<16;++i){
            const int cr = i*8 + (t>>5);
            const int ch = t & 31;
            ushort4 v = *reinterpret_cast<const ushort4*>(
                (char*)Cs + ((cr*256 + ch*8) ^ ((cr & 15) << 3)));
            const int gc = col0 + cr, h = gc >> 6, k = gc & 63;
            *reinterpret_cast<ushort4*>(
                &out[(((size_t)b*HH + h)*DKK + k)*SS + sbase + ch*4]) = v;
        }
    }
}

// ---------------------------------------------------------------------------
// Fused attention: ZERO LDS, ZERO barriers. 256 thr = 4 independent waves,
// each owning 16 q-rows. K/V fragments read directly from global (L1/L2-
// resident via XCD swizzle: each bh's 16 blocks land on one XCD, K+V=256KB).
// Swapped QK^T (mfma(K,Q)): lane owns q-row l&15; row softmax = local sum +
// 2 shfl_xor; fixed shift (validated R10/R11). Pass2: recompute QK, store
// normalized P straight from regs (f32x4, cached stores -> L2 merges), build
// PV A-frag in-register via shfl gather (replicates verified Ps semantics):
//   lane(q,c) slice t2 needs j32=8c..8c+7 = pk[2t2+(c>>1)] of lanes
//   q+16*(2c&3) (lo) and q+16*((2c+1)&3) (hi).
// ---------------------------------------------------------------------------
__global__ __launch_bounds__(256)
void k_attn(const unsigned short* __restrict__ Qb, const unsigned short* __restrict__ Kb,
            const unsigned short* __restrict__ Vtb, const float* __restrict__ at,
            float* __restrict__ attn, unsigned short* __restrict__ ctxb)
{
    const int f   = blockIdx.x;                 // 1024 blocks, %8==0 -> bijective
    const int wk2 = (f & 7)*128 + (f >> 3);     // XCD swizzle
    const int bh  = wk2 >> 4;
    const int q0  = (wk2 & 15) * 64;
    const int b = bh >> 4, h = bh & 15;
    const int t = threadIdx.x, w = t >> 6, l = t & 63;
    const int lq = l & 15;          // q-row within wave's 16 (softmax ownership)
    const int c  = l >> 4;          // 0..3
    const int qg = q0 + w*16;       // wave's q base
    const float alpha = 0.125f / at[0];

    const unsigned short* Qg = Qb  + (size_t)b*SS*DD + (size_t)h*64;   // row stride DD
    const unsigned short* Kg = Kb  + (size_t)b*SS*DD + (size_t)h*64;
    const unsigned short* Vg = Vtb + (size_t)bh*DKK*SS;

    // Q fragments (B-operand): col=lq, k-rows ks*32 + c*8 .. +8
    bf16x8 qf[2];
    #pragma unroll
    for (int ks = 0; ks < 2; ++ks)
        qf[ks] = *reinterpret_cast<const bf16x8*>(
            &Qg[(size_t)(qg + lq)*DD + ks*32 + c*8]);

    // ================= pass 1: row sums (fixed shift 0) =================
    float srow = 0.f;
    for (int jt = 0; jt < SS; jt += JB) {
        f32x4 acc[4];
        #pragma unroll
        for (int n = 0; n < 4; ++n) acc[n] = (f32x4){0.f,0.f,0.f,0.f};
        #pragma unroll
        for (int ks = 0; ks < 2; ++ks) {
            #pragma unroll
            for (int n = 0; n < 4; ++n) {
                bf16x8 kf = *reinterpret_cast<const bf16x8*>(
                    &Kg[(size_t)(jt + n*16 + lq)*DD + ks*32 + c*8]);
                acc[n] = __builtin_amdgcn_mfma_f32_16x16x32_bf16(kf, qf[ks], acc[n], 0, 0, 0);
            }
        }
        #pragma unroll
        for (int n = 0; n < 4; ++n) {
            srow += __expf(acc[n][0]*alpha) + __expf(acc[n][1]*alpha)
                  + __expf(acc[n][2]*alpha) + __expf(acc[n][3]*alpha);
        }
    }
    srow += __shfl_xor(srow, 16, 64);
    srow += __shfl_xor(srow, 32, 64);
    const float sinv = 1.0f / srow;

    // ================= pass 2: recompute + store attn + PV =================
    f32x4 cacc[4];
    #pragma unroll
    for (int dg = 0; dg < 4; ++dg) cacc[dg] = (f32x4){0.f,0.f,0.f,0.f};

    const int lA = lq + ((2*c) & 3)*16;
    const int lB = lq + ((2*c + 1) & 3)*16;
    const bool hi = (c >> 1) != 0;

    for (int jt = 0; jt < SS; jt += JB) {
        f32x4 acc[4];
        #pragma unroll
        for (int n = 0; n < 4; ++n) acc[n] = (f32x4){0.f,0.f,0.f,0.f};
        #pragma unroll
        for (int ks = 0; ks < 2; ++ks) {
            #pragma unroll
            for (int n = 0; n < 4; ++n) {
                bf16x8 kf = *reinterpret_cast<const bf16x8*>(
                    &Kg[(size_t)(jt + n*16 + lq)*DD + ks*32 + c*8]);
                acc[n] = __builtin_amdgcn_mfma_f32_16x16x32_bf16(kf, qf[ks], acc[n], 0, 0, 0);
            }
        }
        // normalized P: direct f32x4 stores (cached; L2 merges 64B segments)
        unsigned pka[4], pkb[4];
        #pragma unroll
        for (int n = 0; n < 4; ++n) {
            float p0 = __expf(acc[n][0]*alpha) * sinv;
            float p1 = __expf(acc[n][1]*alpha) * sinv;
            float p2 = __expf(acc[n][2]*alpha) * sinv;
            float p3 = __expf(acc[n][3]*alpha) * sinv;
            f32x4 fv = (f32x4){p0, p1, p2, p3};
            *reinterpret_cast<f32x4*>(
                &attn[((size_t)bh*SS + qg + lq)*SS + jt + n*16 + c*4]) = fv;
            pka[n] = (unsigned)f2bf(p0) | ((unsigned)f2bf(p1) << 16);
            pkb[n] = (unsigned)f2bf(p2) | ((unsigned)f2bf(p3) << 16);
        }
        // PV: build A-frag per 32-j slice via shfl gather, then 4 mfma
        #pragma unroll
        for (int t2 = 0; t2 < 2; ++t2) {
            const int n0 = 2*t2, n1 = 2*t2 + 1;
            unsigned a0 = (unsigned)__shfl((int)pka[n0], lA, 64);
            unsigned a1 = (unsigned)__shfl((int)pka[n1], lA, 64);
            unsigned b0 = (unsigned)__shfl((int)pkb[n0], lA, 64);
            unsigned b1 = (unsigned)__shfl((int)pkb[n1], lA, 64);
            unsigned c0 = (unsigned)__shfl((int)pka[n0], lB, 64);
            unsigned c1 = (unsigned)__shfl((int)pka[n1], lB, 64);
            unsigned d0 = (unsigned)__shfl((int)pkb[n0], lB, 64);
            unsigned d1 = (unsigned)__shfl((int)pkb[n1], lB, 64);
            int4 uu;
            uu.x = (int)(hi ? a1 : a0);
            uu.y = (int)(hi ? b1 : b0);
            uu.z = (int)(hi ? c1 : c0);
            uu.w = (int)(hi ? d1 : d0);
            bf16x8 pf = *reinterpret_cast<const bf16x8*>(&uu);
            #pragma unroll
            for (int dg = 0; dg < 4; ++dg) {
                bf16x8 vf = *reinterpret_cast<const bf16x8*>(
                    &Vg[(size_t)(dg*16 + lq)*SS + jt + t2*32 + c*8]);
                cacc[dg] = __builtin_amdgcn_mfma_f32_16x16x32_bf16(pf, vf, cacc[dg], 0, 0, 0);
            }
        }
    }

    // ctx store bf16, layout (H,B,S,dk): lane's out q = qg + 4c + r, d = dg*16+lq
    #pragma unroll
    for (int dg = 0; dg < 4; ++dg) {
        const int d = dg*16 + lq;
        #pragma unroll
        for (int r = 0; r < 4; ++r) {
            const int qrow = qg + 4*c + r;
            ctxb[(((size_t)h*BB + b)*SS + qrow)*DKK + d] = f2bf(cacc[dg][r]);
        }
    }
}

// ---------------------------------------------------------------------------
// Out-proj GEMM + bias + residual: y(N,D) f32 = ctx(N,D)bf16 @ wo^T + bo + query
// ---------------------------------------------------------------------------
__global__ __launch_bounds__(256)
void k_gemmo(const unsigned short* __restrict__ X, const unsigned short* __restrict__ W,
             const float* __restrict__ bias, const float* __restrict__ resid,
             float* __restrict__ outf)
{
    __shared__ __align__(16) unsigned short Als[128*32];
    __shared__ __align__(16) unsigned short Bls[128*32];
    const int row0 = blockIdx.x * 128;
    const int col0 = blockIdx.y * 128;
    const int t = threadIdx.x;
    const int w = t >> 6, l = t & 63;
    const int wr = w >> 1, wc = w & 1;

    f32x4 acc[4][4];
    #pragma unroll
    for (int m=0;m<4;++m)
        #pragma unroll
        for (int n=0;n<4;++n) acc[m][n] = (f32x4){0.f,0.f,0.f,0.f};

    const int srow  = l >> 2;
    const int skoff = (l & 3) * 8;

    for (int kt = 0; kt < DD; kt += 32) {
        #pragma unroll
        for (int i=0;i<2;++i) {
            const unsigned short* ga = X + (size_t)(row0 + w*32 + i*16 + srow)*DD + kt + skoff;
            const unsigned short* gb = W + (size_t)(col0 + w*32 + i*16 + srow)*DD + kt + skoff;
            __builtin_amdgcn_global_load_lds((glb_u32*)ga, (lds_u32*)&Als[(w*2+i)*512], 16, 0, 0);
            __builtin_amdgcn_global_load_lds((glb_u32*)gb, (lds_u32*)&Bls[(w*2+i)*512], 16, 0, 0);
        }
        __syncthreads();
        bf16x8 af[4], bfr[4];
        #pragma unroll
        for (int m=0;m<4;++m)
            af[m] = *reinterpret_cast<const bf16x8*>(&Als[(wr*64 + m*16 + (l&15))*32 + (l>>4)*8]);
        #pragma unroll
        for (int n=0;n<4;++n)
            bfr[n] = *reinterpret_cast<const bf16x8*>(&Bls[(wc*64 + n*16 + (l&15))*32 + (l>>4)*8]);
        __builtin_amdgcn_s_setprio(1);
        #pragma unroll
        for (int m=0;m<4;++m)
            #pragma unroll
            for (int n=0;n<4;++n)
                acc[m][n] = __builtin_amdgcn_mfma_f32_16x16x32_bf16(af[m], bfr[n], acc[m][n], 0, 0, 0);
        __builtin_amdgcn_s_setprio(0);
        __syncthreads();
    }

    #pragma unroll
    for (int m=0;m<4;++m){
        const int grow_base = row0 + wr*64 + m*16 + ((l>>4)<<2);
        #pragma unroll
        for (int n=0;n<4;++n){
            const int col = col0 + wc*64 + n*16 + (l&15);
            const float bc = bias[col];
            #pragma unroll
            for (int r=0;r<4;++r){
                const int row = grow_base + r;
                outf[(size_t)row*DD + col] = acc[m][n][r] + bc + resid[(size_t)row*DD + col];
            }
        }
    }
}

// ---------------------------------------------------------------------------
// LayerNorm over last dim (1024), one block per row.
// ---------------------------------------------------------------------------
__global__ __launch_bounds__(256)
void k_ln(const float* __restrict__ y, const float* __restrict__ g,
          const float* __restrict__ be, float* __restrict__ out)
{
    const int row = blockIdx.x;
    const int t = threadIdx.x;
    float4 v = *reinterpret_cast<const float4*>(&y[(size_t)row*DD + t*4]);
    float s  = v.x + v.y + v.z + v.w;
    float ss = v.x*v.x + v.y*v.y + v.z*v.z + v.w*v.w;
    #pragma unroll
    for (int off = 32; off > 0; off >>= 1) {
        s  += __shfl_xor(s,  off, 64);
        ss += __shfl_xor(ss, off, 64);
    }
    __shared__ float red[8];
    const int lane = t & 63, wid = t >> 6;
    if (lane == 0) { red[wid] = s; red[4+wid] = ss; }
    __syncthreads();
    const float S1 = red[0]+red[1]+red[2]+red[3];
    const float S2 = red[4]+red[5]+red[6]+red[7];
    const float mu  = S1 * (1.0f/DD);
    const float var = fmaxf(S2 * (1.0f/DD) - mu*mu, 0.0f);
    const float rstd = rsqrtf(var + LN_EPS);
    float4 gv = *reinterpret_cast<const float4*>(&g[t*4]);
    float4 bv = *reinterpret_cast<const float4*>(&be[t*4]);
    float4 o;
    o.x = (v.x - mu)*rstd*gv.x + bv.x;
    o.y = (v.y - mu)*rstd*gv.y + bv.y;
    o.z = (v.z - mu)*rstd*gv.z + bv.z;
    o.w = (v.w - mu)*rstd*gv.w + bv.w;
    *reinterpret_cast<float4*>(&out[(size_t)row*DD + t*4]) = o;
}

// ---------------------------------------------------------------------------
extern "C" void kernel_launch(void* const* d_in, const int* in_sizes, int n_in,
                              void* d_out, int out_size, void* d_ws, size_t ws_size,
                              hipStream_t stream) {
    const float* query = (const float*)d_in[0];
    const float* key   = (const float*)d_in[1];
    const float* value = (const float*)d_in[2];
    const float* wq = (const float*)d_in[3];
    const float* bq = (const float*)d_in[4];
    const float* wk = (const float*)d_in[5];
    const float* bk = (const float*)d_in[6];
    const float* wv = (const float*)d_in[7];
    const float* bv = (const float*)d_in[8];
    const float* wo = (const float*)d_in[9];
    const float* bo = (const float*)d_in[10];
    // d_in[11] temporal_bias: constant along softmax axis -> softmax-invariant
    const float* at = (const float*)d_in[12];
    const float* g  = (const float*)d_in[13];
    const float* be = (const float*)d_in[14];

    float* out_ln = (float*)d_out;
    float* attn   = (float*)d_out + (size_t)NN*DD;

    char* wsb = (char*)d_ws;
    unsigned short* xq   = (unsigned short*)(wsb);                    // 24 MB: xq,xk,xv
    unsigned short* Qb   = (unsigned short*)(wsb + ((size_t)24<<20)); // 24 MB: Qb,Kb,Vtb
    unsigned short* Kb   = (unsigned short*)(wsb + ((size_t)32<<20));
    unsigned short* Vtb  = (unsigned short*)(wsb + ((size_t)40<<20));
    unsigned short* ctxb = (unsigned short*)(wsb + ((size_t)48<<20)); // 8 MB
    unsigned short* wqb  = (unsigned short*)(wsb + ((size_t)56<<20)); // 8 MB: wq,wk,wv,wo
    float*          y    = (float*)(wsb);                             // 16 MB, over dead xq/xk

    k_cvt_all<<<8192, 256, 0, stream>>>(query, key, value, wq, wk, wv, wo, xq, wqb);

    k_gemmqkv<<<dim3(32, 8, 3), 256, 0, stream>>>(xq, wqb, bq, bk, bv, Qb);

    k_attn<<<dim3(1024), 256, 0, stream>>>(Qb, Kb, Vtb, at, attn, ctxb);

    k_gemmo<<<dim3(32, 8), 256, 0, stream>>>(ctxb, wqb + (size_t)3*DD*DD, bo, query, y);

    k_ln<<<NN, 256, 0, stream>>>(y, g, be, out_ln);
}

// Round 13
// 192.344 us; speedup vs baseline: 1.5366x; 1.5366x over previous
//
#include <hip/hip_runtime.h>
#include <math.h>

#define BB 4
#define SS 1024
#define DD 1024
#define HH 16
#define DKK 64
#define NN (BB*SS)          // 4096 rows
#define LN_EPS 1e-5f
#define QB 128
#define JB 64

typedef __attribute__((ext_vector_type(8))) short bf16x8;
typedef __attribute__((ext_vector_type(4))) float f32x4;
typedef __attribute__((address_space(3))) unsigned int lds_u32;
typedef const __attribute__((address_space(1))) unsigned int glb_u32;

static __device__ __forceinline__ unsigned short f2bf(float x){
    unsigned int u = __float_as_uint(x);
    u += 0x7fff + ((u >> 16) & 1);     // round-to-nearest-even
    return (unsigned short)(u >> 16);
}
static __device__ __forceinline__ int swzp(int q){   // Ps swizzle (bits 4-6)
    return ((q & 7) << 4) ^ ((q & 8) << 2);
}
// raw barrier: lgkmcnt(0) only — NO vmcnt drain (stores stay in flight).
static __device__ __forceinline__ void sync_lds_only(){
    __builtin_amdgcn_sched_barrier(0);
    asm volatile("s_waitcnt lgkmcnt(0)" ::: "memory");
    __builtin_amdgcn_s_barrier();
    __builtin_amdgcn_sched_barrier(0);
}

// ---------------------------------------------------------------------------
// weight cvt only (input cvt fused into k_gemmqkv). grid (512, 4).
// ---------------------------------------------------------------------------
__global__ __launch_bounds__(256)
void k_cvt_w(const float* __restrict__ w0, const float* __restrict__ w1,
             const float* __restrict__ w2, const float* __restrict__ w3,
             unsigned short* __restrict__ out){
    const int z = blockIdx.y;
    const float* src = (z == 0) ? w0 : (z == 1) ? w1 : (z == 2) ? w2 : w3;
    const size_t i = ((size_t)blockIdx.x*256 + threadIdx.x)*8;
    float4 a = *reinterpret_cast<const float4*>(&src[i]);
    float4 b = *reinterpret_cast<const float4*>(&src[i+4]);
    int4 w;
    w.x = (int)((unsigned)f2bf(a.x) | ((unsigned)f2bf(a.y) << 16));
    w.y = (int)((unsigned)f2bf(a.z) | ((unsigned)f2bf(a.w) << 16));
    w.z = (int)((unsigned)f2bf(b.x) | ((unsigned)f2bf(b.y) << 16));
    w.w = (int)((unsigned)f2bf(b.z) | ((unsigned)f2bf(b.w) << 16));
    *reinterpret_cast<int4*>(&out[(size_t)z*DD*DD + i]) = w;
}

// ---------------------------------------------------------------------------
// Unified QKV projection GEMM, grid (32, 8, 3).  z selects {Q,K,V}.
// A read DIRECTLY from f32 inputs (fused cvt): reg-stage f32->bf16->LDS,
// same LDS layout as before (2-way aliasing, free). B via global_load_lds.
// z<2: bf16 out row-major (N,D).   z==2: bf16 out transposed (B,H,dk,S).
// ---------------------------------------------------------------------------
__global__ __launch_bounds__(256)
void k_gemmqkv(const float* __restrict__ q_in, const float* __restrict__ k_in,
               const float* __restrict__ v_in, const unsigned short* __restrict__ Wb,
               const float* __restrict__ b0, const float* __restrict__ b1,
               const float* __restrict__ b2, unsigned short* __restrict__ outb)
{
    __shared__ __align__(16) unsigned short Als[128*32];
    __shared__ __align__(16) unsigned short Bls[128*32];
    __shared__ __align__(16) unsigned short Cs[128*128];
    const int z = blockIdx.z;
    const float* Xf = (z == 0) ? q_in : (z == 1) ? k_in : v_in;
    const unsigned short* W = Wb + (size_t)z*DD*DD;
    const float* bias = (z == 0) ? b0 : (z == 1) ? b1 : b2;
    unsigned short* out = outb + (size_t)z*NN*DD;

    const int row0 = blockIdx.x * 128;
    const int col0 = blockIdx.y * 128;
    const int t = threadIdx.x;
    const int w = t >> 6, l = t & 63;
    const int wr = w >> 1, wc = w & 1;

    f32x4 acc[4][4];
    #pragma unroll
    for (int m=0;m<4;++m)
        #pragma unroll
        for (int n=0;n<4;++n) acc[m][n] = (f32x4){0.f,0.f,0.f,0.f};

    const int srow  = l >> 2;
    const int skoff = (l & 3) * 8;

    for (int kt = 0; kt < DD; kt += 32) {
        #pragma unroll
        for (int i=0;i<2;++i) {
            // A: fused f32->bf16 reg-staging (same dest layout as lds-direct)
            const float* ga = Xf + (size_t)(row0 + w*32 + i*16 + srow)*DD + kt + skoff;
            float4 a0 = *reinterpret_cast<const float4*>(ga);
            float4 a1 = *reinterpret_cast<const float4*>(ga + 4);
            int4 aw;
            aw.x = (int)((unsigned)f2bf(a0.x) | ((unsigned)f2bf(a0.y) << 16));
            aw.y = (int)((unsigned)f2bf(a0.z) | ((unsigned)f2bf(a0.w) << 16));
            aw.z = (int)((unsigned)f2bf(a1.x) | ((unsigned)f2bf(a1.y) << 16));
            aw.w = (int)((unsigned)f2bf(a1.z) | ((unsigned)f2bf(a1.w) << 16));
            *reinterpret_cast<int4*>(&Als[(size_t)(w*2+i)*512 + (size_t)l*8]) = aw;
            // B: async direct-to-LDS (bf16 weights)
            const unsigned short* gb = W + (size_t)(col0 + w*32 + i*16 + srow)*DD + kt + skoff;
            __builtin_amdgcn_global_load_lds((glb_u32*)gb, (lds_u32*)&Bls[(w*2+i)*512], 16, 0, 0);
        }
        __syncthreads();
        bf16x8 af[4], bfr[4];
        #pragma unroll
        for (int m=0;m<4;++m)
            af[m] = *reinterpret_cast<const bf16x8*>(&Als[(wr*64 + m*16 + (l&15))*32 + (l>>4)*8]);
        #pragma unroll
        for (int n=0;n<4;++n)
            bfr[n] = *reinterpret_cast<const bf16x8*>(&Bls[(wc*64 + n*16 + (l&15))*32 + (l>>4)*8]);
        __builtin_amdgcn_s_setprio(1);
        #pragma unroll
        for (int m=0;m<4;++m)
            #pragma unroll
            for (int n=0;n<4;++n)
                acc[m][n] = __builtin_amdgcn_mfma_f32_16x16x32_bf16(af[m], bfr[n], acc[m][n], 0, 0, 0);
        __builtin_amdgcn_s_setprio(0);
        __syncthreads();
    }

    // ---- epilogue through LDS (C/D layout: col=lane&15, row=(lane>>4)*4+reg) ----
    if (z < 2) {
        #pragma unroll
        for (int m=0;m<4;++m){
            const int trb = wr*64 + m*16 + ((l>>4)<<2);
            #pragma unroll
            for (int n=0;n<4;++n){
                const int tc = wc*64 + n*16 + (l&15);
                const float bc = bias[col0 + tc];
                #pragma unroll
                for (int r=0;r<4;++r){
                    const int tr = trb + r;
                    *reinterpret_cast<unsigned short*>(
                        (char*)Cs + ((tr*256 + tc*2) ^ ((tr & 12) << 3))) = f2bf(acc[m][n][r] + bc);
                }
            }
        }
        __syncthreads();
        #pragma unroll
        for (int i=0;i<8;++i){
            const int slot = i*256 + t;
            const int r2 = slot >> 4, g = slot & 15;
            int4 v = *reinterpret_cast<const int4*>(
                (char*)Cs + ((r2*256 + g*16) ^ ((r2 & 12) << 3)));
            *reinterpret_cast<int4*>(&out[(size_t)(row0 + r2)*DD + col0 + g*8]) = v;
        }
    } else {
        #pragma unroll
        for (int m=0;m<4;++m){
            const int trb = wr*64 + m*16 + ((l>>4)<<2);
            #pragma unroll
            for (int n=0;n<4;++n){
                const int tc = wc*64 + n*16 + (l&15);
                const float bc = bias[col0 + tc];
                ushort4 pk;
                pk.x = f2bf(acc[m][n][0] + bc);
                pk.y = f2bf(acc[m][n][1] + bc);
                pk.z = f2bf(acc[m][n][2] + bc);
                pk.w = f2bf(acc[m][n][3] + bc);
                *reinterpret_cast<ushort4*>(
                    (char*)Cs + ((tc*256 + trb*2) ^ ((tc & 15) << 3))) = pk;
            }
        }
        __syncthreads();
        const int b = row0 >> 10;
        const int sbase = row0 & 1023;
        #pragma unroll
        for (int i=0;i<16;++i){
            const int cr = i*8 + (t>>5);
            const int ch = t & 31;
            ushort4 v = *reinterpret_cast<const ushort4*>(
                (char*)Cs + ((cr*256 + ch*8) ^ ((cr & 15) << 3)));
            const int gc = col0 + cr, h = gc >> 6, k = gc & 63;
            *reinterpret_cast<ushort4*>(
                &out[(((size_t)b*HH + h)*DKK + k)*SS + sbase + ch*4]) = v;
        }
    }
}

// ---------------------------------------------------------------------------
// Fused attention (R9 proven structure + FIXED-SHIFT softmax, validated
// R10-R12). 512 threads (8 waves), q-tile 128 rows, double-buffered K/V.
// Pass 1: QK^T MFMA -> lane-local sum of exp (NO max tracking); one 2-shfl
// reduce after the loop. Pass 2: recompute, P=exp(s*a)*sinv -> Ps bf16,
// PV MFMA, full-line attn stores; raw barriers (no vmcnt drain).
// ---------------------------------------------------------------------------
__global__ __launch_bounds__(512)
void k_attn(const unsigned short* __restrict__ Qb, const unsigned short* __restrict__ Kb,
            const unsigned short* __restrict__ Vtb, const float* __restrict__ at,
            float* __restrict__ attn, unsigned short* __restrict__ ctxb)
{
    __shared__ __align__(16) unsigned short Qs[QB*64];      // 16 KB
    __shared__ __align__(16) unsigned short Ks[2][JB*64];   // 2x8 KB
    __shared__ __align__(16) unsigned short Vs[2][DKK*JB];  // 2x8 KB, V^T [d][j]
    __shared__ __align__(16) unsigned short Ps[QB*JB];      // 16 KB
    const int f   = blockIdx.x;                // 512 blocks, 512%8==0 -> bijective
    const int wk2 = (f & 7)*64 + (f >> 3);     // XCD swizzle
    const int bh  = wk2 >> 3;
    const int q0  = (wk2 & 7) * QB;
    const int b = bh >> 4, h = bh & 15;
    const int t = threadIdx.x, w = t >> 6, l = t & 63;
    const float alpha = 0.125f / at[0];

    const unsigned short* Qg = Qb  + (size_t)b*SS*DD + (size_t)h*64;   // row stride DD
    const unsigned short* Kg = Kb  + (size_t)b*SS*DD + (size_t)h*64;
    const unsigned short* Vg = Vtb + (size_t)bh*DKK*SS;

    const int sj  = t >> 3;          // 0..63  K/V staging row
    const int skc = (t & 7) * 8;     // elem offset within row

    // ---- stage Q tile (once) + K tile 0, swizzled ----
    #pragma unroll
    for (int p = 0; p < 2; ++p) {
        const int c = t + p*512;
        const int q = c >> 3, kc = (c & 7) * 8;
        int4 v = *reinterpret_cast<const int4*>(&Qg[(size_t)(q0 + q)*DD + kc]);
        *reinterpret_cast<int4*>((char*)Qs + ((q*128 + kc*2) ^ ((q & 7) << 4))) = v;
    }
    {
        int4 kv = *reinterpret_cast<const int4*>(&Kg[(size_t)sj*DD + skc]);
        *reinterpret_cast<int4*>((char*)Ks[0] + ((sj*128 + skc*2) ^ ((sj & 7) << 4))) = kv;
    }
    __syncthreads();
    bf16x8 qf[2];
    {
        const int q = w*16 + (l & 15);
        #pragma unroll
        for (int ks = 0; ks < 2; ++ks)
            qf[ks] = *reinterpret_cast<const bf16x8*>(
                (char*)Qs + ((q*128 + (l>>4)*16 + ks*64) ^ ((q & 7) << 4)));
    }

    // ================= pass 1: row sums (FIXED SHIFT, no max) =================
    float srow = 0.f;
    int cur = 0;
    for (int j0 = 0; j0 < SS; j0 += JB) {
        int4 knext;
        const bool more = (j0 + JB < SS);
        if (more)
            knext = *reinterpret_cast<const int4*>(&Kg[(size_t)(j0 + JB + sj)*DD + skc]);
        f32x4 acc[4];
        #pragma unroll
        for (int n = 0; n < 4; ++n) acc[n] = (f32x4){0.f,0.f,0.f,0.f};
        __builtin_amdgcn_s_setprio(1);
        #pragma unroll
        for (int ks = 0; ks < 2; ++ks) {
            #pragma unroll
            for (int n = 0; n < 4; ++n) {
                const int j = n*16 + (l & 15);
                bf16x8 kf = *reinterpret_cast<const bf16x8*>(
                    (char*)Ks[cur] + ((j*128 + (l>>4)*16 + ks*64) ^ ((j & 7) << 4)));
                acc[n] = __builtin_amdgcn_mfma_f32_16x16x32_bf16(kf, qf[ks], acc[n], 0, 0, 0);
            }
        }
        __builtin_amdgcn_s_setprio(0);
        float ps = 0.f;
        #pragma unroll
        for (int n = 0; n < 4; ++n)
            #pragma unroll
            for (int r = 0; r < 4; ++r) ps += __expf(acc[n][r]*alpha);
        srow += ps;
        if (more)
            *reinterpret_cast<int4*>((char*)Ks[cur^1] + ((sj*128 + skc*2) ^ ((sj & 7) << 4))) = knext;
        __syncthreads();
        cur ^= 1;
    }
    srow += __shfl_xor(srow, 16, 64);
    srow += __shfl_xor(srow, 32, 64);
    const float sinv = 1.0f / srow;

    // ================= pass 2: recompute + attn write + PV =================
    f32x4 cacc[4];
    #pragma unroll
    for (int n = 0; n < 4; ++n) cacc[n] = (f32x4){0.f,0.f,0.f,0.f};

    // prologue: restage K/V tile 0 into buf 0; preload tile-1 regs
    int4 knext, vnext;
    {
        int4 kv = *reinterpret_cast<const int4*>(&Kg[(size_t)sj*DD + skc]);
        int4 vv = *reinterpret_cast<const int4*>(&Vg[(size_t)sj*SS + skc]);
        *reinterpret_cast<int4*>((char*)Ks[0] + ((sj*128 + skc*2) ^ ((sj & 7) << 4))) = kv;
        *reinterpret_cast<int4*>((char*)Vs[0] + ((sj*128 + skc*2) ^ ((sj & 7) << 4))) = vv;
        knext = *reinterpret_cast<const int4*>(&Kg[(size_t)(JB + sj)*DD + skc]);
        vnext = *reinterpret_cast<const int4*>(&Vg[(size_t)sj*SS + JB + skc]);
    }
    __syncthreads();

    cur = 0;
    for (int j0 = 0; j0 < SS; j0 += JB) {
        const bool more = (j0 + JB < SS);
        f32x4 acc[4];
        #pragma unroll
        for (int n = 0; n < 4; ++n) acc[n] = (f32x4){0.f,0.f,0.f,0.f};
        __builtin_amdgcn_s_setprio(1);
        #pragma unroll
        for (int ks = 0; ks < 2; ++ks) {
            #pragma unroll
            for (int n = 0; n < 4; ++n) {
                const int j = n*16 + (l & 15);
                bf16x8 kf = *reinterpret_cast<const bf16x8*>(
                    (char*)Ks[cur] + ((j*128 + (l>>4)*16 + ks*64) ^ ((j & 7) << 4)));
                acc[n] = __builtin_amdgcn_mfma_f32_16x16x32_bf16(kf, qf[ks], acc[n], 0, 0, 0);
            }
        }
        __builtin_amdgcn_s_setprio(0);
        // P = exp(s*alpha)*sinv; pack 4 consecutive j -> ds_write_b64
        {
            const int q = w*16 + (l & 15);
            const int c = l >> 4;
            #pragma unroll
            for (int n = 0; n < 4; ++n) {
                float p0 = __expf(acc[n][0]*alpha) * sinv;
                float p1 = __expf(acc[n][1]*alpha) * sinv;
                float p2 = __expf(acc[n][2]*alpha) * sinv;
                float p3 = __expf(acc[n][3]*alpha) * sinv;
                int2 pk;
                pk.x = (int)((unsigned)f2bf(p0) | ((unsigned)f2bf(p1) << 16));
                pk.y = (int)((unsigned)f2bf(p2) | ((unsigned)f2bf(p3) << 16));
                *reinterpret_cast<int2*>(
                    (char*)Ps + ((q*128 + n*32 + c*8) ^ swzp(q))) = pk;
            }
        }
        // stage next K/V from regs (loaded before last tile's stores)
        if (more) {
            *reinterpret_cast<int4*>((char*)Ks[cur^1] + ((sj*128 + skc*2) ^ ((sj & 7) << 4))) = knext;
            *reinterpret_cast<int4*>((char*)Vs[cur^1] + ((sj*128 + skc*2) ^ ((sj & 7) << 4))) = vnext;
        }
        sync_lds_only();
        // issue loads for tile t+2 (before this tile's stores)
        if (j0 + 2*JB < SS) {
            knext = *reinterpret_cast<const int4*>(&Kg[(size_t)(j0 + 2*JB + sj)*DD + skc]);
            vnext = *reinterpret_cast<const int4*>(&Vg[(size_t)sj*SS + j0 + 2*JB + skc]);
        }
        // PV MFMA
        __builtin_amdgcn_s_setprio(1);
        #pragma unroll
        for (int ks = 0; ks < 2; ++ks) {
            const int qr = w*16 + (l & 15);
            bf16x8 pf = *reinterpret_cast<const bf16x8*>(
                (char*)Ps + ((qr*128 + (l>>4)*16 + ks*64) ^ swzp(qr)));
            #pragma unroll
            for (int n = 0; n < 4; ++n) {
                const int d = n*16 + (l & 15);
                bf16x8 vf = *reinterpret_cast<const bf16x8*>(
                    (char*)Vs[cur] + ((d*128 + (l>>4)*16 + ks*64) ^ ((d & 7) << 4)));
                cacc[n] = __builtin_amdgcn_mfma_f32_16x16x32_bf16(pf, vf, cacc[n], 0, 0, 0);
            }
        }
        __builtin_amdgcn_s_setprio(0);
        // full-line attn store: pass i -> row i*32+(t>>4); 16 lanes = 256B line
        #pragma unroll
        for (int i = 0; i < 4; ++i) {
            const int sr = i*32 + (t >> 4);
            const int j4 = (t & 15) * 4;
            int2 u = *reinterpret_cast<const int2*>(
                (char*)Ps + ((sr*128 + j4*2) ^ swzp(sr)));
            f32x4 fv;
            fv.x = __uint_as_float(((unsigned)u.x) << 16);
            fv.y = __uint_as_float(((unsigned)u.x) & 0xffff0000u);
            fv.z = __uint_as_float(((unsigned)u.y) << 16);
            fv.w = __uint_as_float(((unsigned)u.y) & 0xffff0000u);
            __builtin_nontemporal_store(fv, reinterpret_cast<f32x4*>(
                &attn[((size_t)bh*SS + q0 + sr)*SS + j0 + j4]));
        }
        sync_lds_only();
        cur ^= 1;
    }

    // ctx store bf16, layout (H,B,S,dk)
    #pragma unroll
    for (int n = 0; n < 4; ++n) {
        const int d = n*16 + (l & 15);
        #pragma unroll
        for (int r = 0; r < 4; ++r) {
            const int q = q0 + w*16 + (l>>4)*4 + r;
            ctxb[(((size_t)h*BB + b)*SS + q)*DKK + d] = f2bf(cacc[n][r]);
        }
    }
}

// ---------------------------------------------------------------------------
// Out-proj GEMM + bias + residual: y(N,D) f32 = ctx(N,D)bf16 @ wo^T + bo + query
// ---------------------------------------------------------------------------
__global__ __launch_bounds__(256)
void k_gemmo(const unsigned short* __restrict__ X, const unsigned short* __restrict__ W,
             const float* __restrict__ bias, const float* __restrict__ resid,
             float* __restrict__ outf)
{
    __shared__ __align__(16) unsigned short Als[128*32];
    __shared__ __align__(16) unsigned short Bls[128*32];
    const int row0 = blockIdx.x * 128;
    const int col0 = blockIdx.y * 128;
    const int t = threadIdx.x;
    const int w = t >> 6, l = t & 63;
    const int wr = w >> 1, wc = w & 1;

    f32x4 acc[4][4];
    #pragma unroll
    for (int m=0;m<4;++m)
        #pragma unroll
        for (int n=0;n<4;++n) acc[m][n] = (f32x4){0.f,0.f,0.f,0.f};

    const int srow  = l >> 2;
    const int skoff = (l & 3) * 8;

    for (int kt = 0; kt < DD; kt += 32) {
        #pragma unroll
        for (int i=0;i<2;++i) {
            const unsigned short* ga = X + (size_t)(row0 + w*32 + i*16 + srow)*DD + kt + skoff;
            const unsigned short* gb = W + (size_t)(col0 + w*32 + i*16 + srow)*DD + kt + skoff;
            __builtin_amdgcn_global_load_lds((glb_u32*)ga, (lds_u32*)&Als[(w*2+i)*512], 16, 0, 0);
            __builtin_amdgcn_global_load_lds((glb_u32*)gb, (lds_u32*)&Bls[(w*2+i)*512], 16, 0, 0);
        }
        __syncthreads();
        bf16x8 af[4], bfr[4];
        #pragma unroll
        for (int m=0;m<4;++m)
            af[m] = *reinterpret_cast<const bf16x8*>(&Als[(wr*64 + m*16 + (l&15))*32 + (l>>4)*8]);
        #pragma unroll
        for (int n=0;n<4;++n)
            bfr[n] = *reinterpret_cast<const bf16x8*>(&Bls[(wc*64 + n*16 + (l&15))*32 + (l>>4)*8]);
        __builtin_amdgcn_s_setprio(1);
        #pragma unroll
        for (int m=0;m<4;++m)
            #pragma unroll
            for (int n=0;n<4;++n)
                acc[m][n] = __builtin_amdgcn_mfma_f32_16x16x32_bf16(af[m], bfr[n], acc[m][n], 0, 0, 0);
        __builtin_amdgcn_s_setprio(0);
        __syncthreads();
    }

    #pragma unroll
    for (int m=0;m<4;++m){
        const int grow_base = row0 + wr*64 + m*16 + ((l>>4)<<2);
        #pragma unroll
        for (int n=0;n<4;++n){
            const int col = col0 + wc*64 + n*16 + (l&15);
            const float bc = bias[col];
            #pragma unroll
            for (int r=0;r<4;++r){
                const int row = grow_base + r;
                outf[(size_t)row*DD + col] = acc[m][n][r] + bc + resid[(size_t)row*DD + col];
            }
        }
    }
}

// ---------------------------------------------------------------------------
// LayerNorm over last dim (1024), one block per row.
// ---------------------------------------------------------------------------
__global__ __launch_bounds__(256)
void k_ln(const float* __restrict__ y, const float* __restrict__ g,
          const float* __restrict__ be, float* __restrict__ out)
{
    const int row = blockIdx.x;
    const int t = threadIdx.x;
    float4 v = *reinterpret_cast<const float4*>(&y[(size_t)row*DD + t*4]);
    float s  = v.x + v.y + v.z + v.w;
    float ss = v.x*v.x + v.y*v.y + v.z*v.z + v.w*v.w;
    #pragma unroll
    for (int off = 32; off > 0; off >>= 1) {
        s  += __shfl_xor(s,  off, 64);
        ss += __shfl_xor(ss, off, 64);
    }
    __shared__ float red[8];
    const int lane = t & 63, wid = t >> 6;
    if (lane == 0) { red[wid] = s; red[4+wid] = ss; }
    __syncthreads();
    const float S1 = red[0]+red[1]+red[2]+red[3];
    const float S2 = red[4]+red[5]+red[6]+red[7];
    const float mu  = S1 * (1.0f/DD);
    const float var = fmaxf(S2 * (1.0f/DD) - mu*mu, 0.0f);
    const float rstd = rsqrtf(var + LN_EPS);
    float4 gv = *reinterpret_cast<const float4*>(&g[t*4]);
    float4 bv = *reinterpret_cast<const float4*>(&be[t*4]);
    float4 o;
    o.x = (v.x - mu)*rstd*gv.x + bv.x;
    o.y = (v.y - mu)*rstd*gv.y + bv.y;
    o.z = (v.z - mu)*rstd*gv.z + bv.z;
    o.w = (v.w - mu)*rstd*gv.w + bv.w;
    *reinterpret_cast<float4*>(&out[(size_t)row*DD + t*4]) = o;
}

// ---------------------------------------------------------------------------
extern "C" void kernel_launch(void* const* d_in, const int* in_sizes, int n_in,
                              void* d_out, int out_size, void* d_ws, size_t ws_size,
                              hipStream_t stream) {
    const float* query = (const float*)d_in[0];
    const float* key   = (const float*)d_in[1];
    const float* value = (const float*)d_in[2];
    const float* wq = (const float*)d_in[3];
    const float* bq = (const float*)d_in[4];
    const float* wk = (const float*)d_in[5];
    const float* bk = (const float*)d_in[6];
    const float* wv = (const float*)d_in[7];
    const float* bv = (const float*)d_in[8];
    const float* wo = (const float*)d_in[9];
    const float* bo = (const float*)d_in[10];
    // d_in[11] temporal_bias: constant along softmax axis -> softmax-invariant
    const float* at = (const float*)d_in[12];
    const float* g  = (const float*)d_in[13];
    const float* be = (const float*)d_in[14];

    float* out_ln = (float*)d_out;
    float* attn   = (float*)d_out + (size_t)NN*DD;

    char* wsb = (char*)d_ws;
    float*          y    = (float*)(wsb);                             // 16 MB
    unsigned short* Qb   = (unsigned short*)(wsb + ((size_t)24<<20)); // 8 MB
    unsigned short* Kb   = (unsigned short*)(wsb + ((size_t)32<<20)); // 8 MB
    unsigned short* Vtb  = (unsigned short*)(wsb + ((size_t)40<<20)); // 8 MB (B,H,dk,S)
    unsigned short* ctxb = (unsigned short*)(wsb + ((size_t)48<<20)); // 8 MB
    unsigned short* wqb  = (unsigned short*)(wsb + ((size_t)56<<20)); // 8 MB: wq,wk,wv,wo

    k_cvt_w<<<dim3(512, 4), 256, 0, stream>>>(wq, wk, wv, wo, wqb);

    k_gemmqkv<<<dim3(32, 8, 3), 256, 0, stream>>>(query, key, value, wqb,
                                                  bq, bk, bv, Qb);

    k_attn<<<dim3(512), 512, 0, stream>>>(Qb, Kb, Vtb, at, attn, ctxb);

    k_gemmo<<<dim3(32, 8), 256, 0, stream>>>(ctxb, wqb + (size_t)3*DD*DD, bo, query, y);

    k_ln<<<NN, 256, 0, stream>>>(y, g, be, out_ln);
}

// Round 14
// 174.694 us; speedup vs baseline: 1.6919x; 1.1010x over previous
//
#include <hip/hip_runtime.h>
#include <math.h>

#define BB 4
#define SS 1024
#define DD 1024
#define HH 16
#define DKK 64
#define NN (BB*SS)          // 4096 rows
#define LN_EPS 1e-5f
#define QB 128
#define JB 64

typedef __attribute__((ext_vector_type(8))) short bf16x8;
typedef __attribute__((ext_vector_type(4))) float f32x4;
typedef __attribute__((address_space(3))) unsigned int lds_u32;
typedef const __attribute__((address_space(1))) unsigned int glb_u32;

static __device__ __forceinline__ unsigned short f2bf(float x){
    unsigned int u = __float_as_uint(x);
    u += 0x7fff + ((u >> 16) & 1);     // round-to-nearest-even
    return (unsigned short)(u >> 16);
}
static __device__ __forceinline__ int swzp(int q){   // Ps swizzle (bits 4-6)
    return ((q & 7) << 4) ^ ((q & 8) << 2);
}
// raw barrier: lgkmcnt(0) only — NO vmcnt drain (stores stay in flight).
static __device__ __forceinline__ void sync_lds_only(){
    __builtin_amdgcn_sched_barrier(0);
    asm volatile("s_waitcnt lgkmcnt(0)" ::: "memory");
    __builtin_amdgcn_s_barrier();
    __builtin_amdgcn_sched_barrier(0);
}

// ---------------------------------------------------------------------------
// all f32->bf16 conversions in one kernel. grid 8192:
// [0,6144): q/k/v (2048 each) -> xout slots; [6144,8192): wq/wk/wv/wo (512 each)
// ---------------------------------------------------------------------------
__global__ __launch_bounds__(256)
void k_cvt_all(const float* __restrict__ q, const float* __restrict__ k,
               const float* __restrict__ v, const float* __restrict__ w0,
               const float* __restrict__ w1, const float* __restrict__ w2,
               const float* __restrict__ w3, unsigned short* __restrict__ xout,
               unsigned short* __restrict__ wout){
    const int bidx = blockIdx.x;
    const float* src; unsigned short* dst; size_t i;
    if (bidx < 6144) {
        const int z = bidx >> 11, bi = bidx & 2047;
        src = (z == 0) ? q : (z == 1) ? k : v;
        dst = xout + (size_t)z*NN*DD;
        i = ((size_t)bi*256 + threadIdx.x)*8;
    } else {
        const int z = (bidx - 6144) >> 9, bi = (bidx - 6144) & 511;
        src = (z == 0) ? w0 : (z == 1) ? w1 : (z == 2) ? w2 : w3;
        dst = wout + (size_t)z*DD*DD;
        i = ((size_t)bi*256 + threadIdx.x)*8;
    }
    float4 a = *reinterpret_cast<const float4*>(&src[i]);
    float4 b = *reinterpret_cast<const float4*>(&src[i+4]);
    int4 w;
    w.x = (int)((unsigned)f2bf(a.x) | ((unsigned)f2bf(a.y) << 16));
    w.y = (int)((unsigned)f2bf(a.z) | ((unsigned)f2bf(a.w) << 16));
    w.z = (int)((unsigned)f2bf(b.x) | ((unsigned)f2bf(b.y) << 16));
    w.w = (int)((unsigned)f2bf(b.z) | ((unsigned)f2bf(b.w) << 16));
    *reinterpret_cast<int4*>(&dst[i]) = w;
}

// ---------------------------------------------------------------------------
// Unified QKV projection GEMM, grid (32, 8, 3).  z selects {Q,K,V}.
// z<2: bf16 out row-major (N,D).   z==2: bf16 out transposed (B,H,dk,S).
// Epilogue bounces through a 32KB LDS tile for coalesced global stores.
// ---------------------------------------------------------------------------
__global__ __launch_bounds__(256)
void k_gemmqkv(const unsigned short* __restrict__ Xb, const unsigned short* __restrict__ Wb,
               const float* __restrict__ b0, const float* __restrict__ b1,
               const float* __restrict__ b2, unsigned short* __restrict__ outb)
{
    __shared__ __align__(16) unsigned short Als[128*32];
    __shared__ __align__(16) unsigned short Bls[128*32];
    __shared__ __align__(16) unsigned short Cs[128*128];
    const int z = blockIdx.z;
    const unsigned short* X = Xb + (size_t)z*NN*DD;
    const unsigned short* W = Wb + (size_t)z*DD*DD;
    const float* bias = (z == 0) ? b0 : (z == 1) ? b1 : b2;
    unsigned short* out = outb + (size_t)z*NN*DD;

    const int row0 = blockIdx.x * 128;
    const int col0 = blockIdx.y * 128;
    const int t = threadIdx.x;
    const int w = t >> 6, l = t & 63;
    const int wr = w >> 1, wc = w & 1;

    f32x4 acc[4][4];
    #pragma unroll
    for (int m=0;m<4;++m)
        #pragma unroll
        for (int n=0;n<4;++n) acc[m][n] = (f32x4){0.f,0.f,0.f,0.f};

    const int srow  = l >> 2;
    const int skoff = (l & 3) * 8;

    for (int kt = 0; kt < DD; kt += 32) {
        #pragma unroll
        for (int i=0;i<2;++i) {
            const unsigned short* ga = X + (size_t)(row0 + w*32 + i*16 + srow)*DD + kt + skoff;
            const unsigned short* gb = W + (size_t)(col0 + w*32 + i*16 + srow)*DD + kt + skoff;
            __builtin_amdgcn_global_load_lds((glb_u32*)ga, (lds_u32*)&Als[(w*2+i)*512], 16, 0, 0);
            __builtin_amdgcn_global_load_lds((glb_u32*)gb, (lds_u32*)&Bls[(w*2+i)*512], 16, 0, 0);
        }
        __syncthreads();
        bf16x8 af[4], bfr[4];
        #pragma unroll
        for (int m=0;m<4;++m)
            af[m] = *reinterpret_cast<const bf16x8*>(&Als[(wr*64 + m*16 + (l&15))*32 + (l>>4)*8]);
        #pragma unroll
        for (int n=0;n<4;++n)
            bfr[n] = *reinterpret_cast<const bf16x8*>(&Bls[(wc*64 + n*16 + (l&15))*32 + (l>>4)*8]);
        __builtin_amdgcn_s_setprio(1);
        #pragma unroll
        for (int m=0;m<4;++m)
            #pragma unroll
            for (int n=0;n<4;++n)
                acc[m][n] = __builtin_amdgcn_mfma_f32_16x16x32_bf16(af[m], bfr[n], acc[m][n], 0, 0, 0);
        __builtin_amdgcn_s_setprio(0);
        __syncthreads();
    }

    // ---- epilogue through LDS (C/D layout: col=lane&15, row=(lane>>4)*4+reg) ----
    if (z < 2) {
        #pragma unroll
        for (int m=0;m<4;++m){
            const int trb = wr*64 + m*16 + ((l>>4)<<2);
            #pragma unroll
            for (int n=0;n<4;++n){
                const int tc = wc*64 + n*16 + (l&15);
                const float bc = bias[col0 + tc];
                #pragma unroll
                for (int r=0;r<4;++r){
                    const int tr = trb + r;
                    *reinterpret_cast<unsigned short*>(
                        (char*)Cs + ((tr*256 + tc*2) ^ ((tr & 12) << 3))) = f2bf(acc[m][n][r] + bc);
                }
            }
        }
        __syncthreads();
        #pragma unroll
        for (int i=0;i<8;++i){
            const int slot = i*256 + t;
            const int r2 = slot >> 4, g = slot & 15;
            int4 v = *reinterpret_cast<const int4*>(
                (char*)Cs + ((r2*256 + g*16) ^ ((r2 & 12) << 3)));
            *reinterpret_cast<int4*>(&out[(size_t)(row0 + r2)*DD + col0 + g*8]) = v;
        }
    } else {
        #pragma unroll
        for (int m=0;m<4;++m){
            const int trb = wr*64 + m*16 + ((l>>4)<<2);
            #pragma unroll
            for (int n=0;n<4;++n){
                const int tc = wc*64 + n*16 + (l&15);
                const float bc = bias[col0 + tc];
                ushort4 pk;
                pk.x = f2bf(acc[m][n][0] + bc);
                pk.y = f2bf(acc[m][n][1] + bc);
                pk.z = f2bf(acc[m][n][2] + bc);
                pk.w = f2bf(acc[m][n][3] + bc);
                *reinterpret_cast<ushort4*>(
                    (char*)Cs + ((tc*256 + trb*2) ^ ((tc & 15) << 3))) = pk;
            }
        }
        __syncthreads();
        const int b = row0 >> 10;
        const int sbase = row0 & 1023;
        #pragma unroll
        for (int i=0;i<16;++i){
            const int cr = i*8 + (t>>5);
            const int ch = t & 31;
            ushort4 v = *reinterpret_cast<const ushort4*>(
                (char*)Cs + ((cr*256 + ch*8) ^ ((cr & 15) << 3)));
            const int gc = col0 + cr, h = gc >> 6, k = gc & 63;
            *reinterpret_cast<ushort4*>(
                &out[(((size_t)b*HH + h)*DKK + k)*SS + sbase + ch*4]) = v;
        }
    }
}

// ---------------------------------------------------------------------------
// Fused attention (R9 proven structure + FIXED-SHIFT softmax, validated
// R10-R12). 512 threads (8 waves), q-tile 128 rows, double-buffered K/V.
// Pass 1: QK^T MFMA -> lane-local sum of exp (NO max tracking); one 2-shfl
// reduce after the loop. Pass 2: recompute, P=exp(s*a)*sinv -> Ps bf16,
// PV MFMA, full-line attn stores; raw barriers (no vmcnt drain).
// ---------------------------------------------------------------------------
__global__ __launch_bounds__(512)
void k_attn(const unsigned short* __restrict__ Qb, const unsigned short* __restrict__ Kb,
            const unsigned short* __restrict__ Vtb, const float* __restrict__ at,
            float* __restrict__ attn, unsigned short* __restrict__ ctxb)
{
    __shared__ __align__(16) unsigned short Qs[QB*64];      // 16 KB
    __shared__ __align__(16) unsigned short Ks[2][JB*64];   // 2x8 KB
    __shared__ __align__(16) unsigned short Vs[2][DKK*JB];  // 2x8 KB, V^T [d][j]
    __shared__ __align__(16) unsigned short Ps[QB*JB];      // 16 KB
    const int f   = blockIdx.x;                // 512 blocks, 512%8==0 -> bijective
    const int wk2 = (f & 7)*64 + (f >> 3);     // XCD swizzle
    const int bh  = wk2 >> 3;
    const int q0  = (wk2 & 7) * QB;
    const int b = bh >> 4, h = bh & 15;
    const int t = threadIdx.x, w = t >> 6, l = t & 63;
    const float alpha = 0.125f / at[0];

    const unsigned short* Qg = Qb  + (size_t)b*SS*DD + (size_t)h*64;   // row stride DD
    const unsigned short* Kg = Kb  + (size_t)b*SS*DD + (size_t)h*64;
    const unsigned short* Vg = Vtb + (size_t)bh*DKK*SS;

    const int sj  = t >> 3;          // 0..63  K/V staging row
    const int skc = (t & 7) * 8;     // elem offset within row

    // ---- stage Q tile (once) + K tile 0, swizzled ----
    #pragma unroll
    for (int p = 0; p < 2; ++p) {
        const int c = t + p*512;
        const int q = c >> 3, kc = (c & 7) * 8;
        int4 v = *reinterpret_cast<const int4*>(&Qg[(size_t)(q0 + q)*DD + kc]);
        *reinterpret_cast<int4*>((char*)Qs + ((q*128 + kc*2) ^ ((q & 7) << 4))) = v;
    }
    {
        int4 kv = *reinterpret_cast<const int4*>(&Kg[(size_t)sj*DD + skc]);
        *reinterpret_cast<int4*>((char*)Ks[0] + ((sj*128 + skc*2) ^ ((sj & 7) << 4))) = kv;
    }
    __syncthreads();
    bf16x8 qf[2];
    {
        const int q = w*16 + (l & 15);
        #pragma unroll
        for (int ks = 0; ks < 2; ++ks)
            qf[ks] = *reinterpret_cast<const bf16x8*>(
                (char*)Qs + ((q*128 + (l>>4)*16 + ks*64) ^ ((q & 7) << 4)));
    }

    // ================= pass 1: row sums (FIXED SHIFT, no max) =================
    float srow = 0.f;
    int cur = 0;
    for (int j0 = 0; j0 < SS; j0 += JB) {
        int4 knext;
        const bool more = (j0 + JB < SS);
        if (more)
            knext = *reinterpret_cast<const int4*>(&Kg[(size_t)(j0 + JB + sj)*DD + skc]);
        f32x4 acc[4];
        #pragma unroll
        for (int n = 0; n < 4; ++n) acc[n] = (f32x4){0.f,0.f,0.f,0.f};
        __builtin_amdgcn_s_setprio(1);
        #pragma unroll
        for (int ks = 0; ks < 2; ++ks) {
            #pragma unroll
            for (int n = 0; n < 4; ++n) {
                const int j = n*16 + (l & 15);
                bf16x8 kf = *reinterpret_cast<const bf16x8*>(
                    (char*)Ks[cur] + ((j*128 + (l>>4)*16 + ks*64) ^ ((j & 7) << 4)));
                acc[n] = __builtin_amdgcn_mfma_f32_16x16x32_bf16(kf, qf[ks], acc[n], 0, 0, 0);
            }
        }
        __builtin_amdgcn_s_setprio(0);
        float ps = 0.f;
        #pragma unroll
        for (int n = 0; n < 4; ++n)
            #pragma unroll
            for (int r = 0; r < 4; ++r) ps += __expf(acc[n][r]*alpha);
        srow += ps;
        if (more)
            *reinterpret_cast<int4*>((char*)Ks[cur^1] + ((sj*128 + skc*2) ^ ((sj & 7) << 4))) = knext;
        __syncthreads();
        cur ^= 1;
    }
    srow += __shfl_xor(srow, 16, 64);
    srow += __shfl_xor(srow, 32, 64);
    const float sinv = 1.0f / srow;

    // ================= pass 2: recompute + attn write + PV =================
    f32x4 cacc[4];
    #pragma unroll
    for (int n = 0; n < 4; ++n) cacc[n] = (f32x4){0.f,0.f,0.f,0.f};

    // prologue: restage K/V tile 0 into buf 0; preload tile-1 regs
    int4 knext, vnext;
    {
        int4 kv = *reinterpret_cast<const int4*>(&Kg[(size_t)sj*DD + skc]);
        int4 vv = *reinterpret_cast<const int4*>(&Vg[(size_t)sj*SS + skc]);
        *reinterpret_cast<int4*>((char*)Ks[0] + ((sj*128 + skc*2) ^ ((sj & 7) << 4))) = kv;
        *reinterpret_cast<int4*>((char*)Vs[0] + ((sj*128 + skc*2) ^ ((sj & 7) << 4))) = vv;
        knext = *reinterpret_cast<const int4*>(&Kg[(size_t)(JB + sj)*DD + skc]);
        vnext = *reinterpret_cast<const int4*>(&Vg[(size_t)sj*SS + JB + skc]);
    }
    __syncthreads();

    cur = 0;
    for (int j0 = 0; j0 < SS; j0 += JB) {
        const bool more = (j0 + JB < SS);
        f32x4 acc[4];
        #pragma unroll
        for (int n = 0; n < 4; ++n) acc[n] = (f32x4){0.f,0.f,0.f,0.f};
        __builtin_amdgcn_s_setprio(1);
        #pragma unroll
        for (int ks = 0; ks < 2; ++ks) {
            #pragma unroll
            for (int n = 0; n < 4; ++n) {
                const int j = n*16 + (l & 15);
                bf16x8 kf = *reinterpret_cast<const bf16x8*>(
                    (char*)Ks[cur] + ((j*128 + (l>>4)*16 + ks*64) ^ ((j & 7) << 4)));
                acc[n] = __builtin_amdgcn_mfma_f32_16x16x32_bf16(kf, qf[ks], acc[n], 0, 0, 0);
            }
        }
        __builtin_amdgcn_s_setprio(0);
        // P = exp(s*alpha)*sinv; pack 4 consecutive j -> ds_write_b64
        {
            const int q = w*16 + (l & 15);
            const int c = l >> 4;
            #pragma unroll
            for (int n = 0; n < 4; ++n) {
                float p0 = __expf(acc[n][0]*alpha) * sinv;
                float p1 = __expf(acc[n][1]*alpha) * sinv;
                float p2 = __expf(acc[n][2]*alpha) * sinv;
                float p3 = __expf(acc[n][3]*alpha) * sinv;
                int2 pk;
                pk.x = (int)((unsigned)f2bf(p0) | ((unsigned)f2bf(p1) << 16));
                pk.y = (int)((unsigned)f2bf(p2) | ((unsigned)f2bf(p3) << 16));
                *reinterpret_cast<int2*>(
                    (char*)Ps + ((q*128 + n*32 + c*8) ^ swzp(q))) = pk;
            }
        }
        // stage next K/V from regs (loaded before last tile's stores)
        if (more) {
            *reinterpret_cast<int4*>((char*)Ks[cur^1] + ((sj*128 + skc*2) ^ ((sj & 7) << 4))) = knext;
            *reinterpret_cast<int4*>((char*)Vs[cur^1] + ((sj*128 + skc*2) ^ ((sj & 7) << 4))) = vnext;
        }
        sync_lds_only();
        // issue loads for tile t+2 (before this tile's stores)
        if (j0 + 2*JB < SS) {
            knext = *reinterpret_cast<const int4*>(&Kg[(size_t)(j0 + 2*JB + sj)*DD + skc]);
            vnext = *reinterpret_cast<const int4*>(&Vg[(size_t)sj*SS + j0 + 2*JB + skc]);
        }
        // PV MFMA
        __builtin_amdgcn_s_setprio(1);
        #pragma unroll
        for (int ks = 0; ks < 2; ++ks) {
            const int qr = w*16 + (l & 15);
            bf16x8 pf = *reinterpret_cast<const bf16x8*>(
                (char*)Ps + ((qr*128 + (l>>4)*16 + ks*64) ^ swzp(qr)));
            #pragma unroll
            for (int n = 0; n < 4; ++n) {
                const int d = n*16 + (l & 15);
                bf16x8 vf = *reinterpret_cast<const bf16x8*>(
                    (char*)Vs[cur] + ((d*128 + (l>>4)*16 + ks*64) ^ ((d & 7) << 4)));
                cacc[n] = __builtin_amdgcn_mfma_f32_16x16x32_bf16(pf, vf, cacc[n], 0, 0, 0);
            }
        }
        __builtin_amdgcn_s_setprio(0);
        // full-line attn store: pass i -> row i*32+(t>>4); 16 lanes = 256B line
        #pragma unroll
        for (int i = 0; i < 4; ++i) {
            const int sr = i*32 + (t >> 4);
            const int j4 = (t & 15) * 4;
            int2 u = *reinterpret_cast<const int2*>(
                (char*)Ps + ((sr*128 + j4*2) ^ swzp(sr)));
            f32x4 fv;
            fv.x = __uint_as_float(((unsigned)u.x) << 16);
            fv.y = __uint_as_float(((unsigned)u.x) & 0xffff0000u);
            fv.z = __uint_as_float(((unsigned)u.y) << 16);
            fv.w = __uint_as_float(((unsigned)u.y) & 0xffff0000u);
            __builtin_nontemporal_store(fv, reinterpret_cast<f32x4*>(
                &attn[((size_t)bh*SS + q0 + sr)*SS + j0 + j4]));
        }
        sync_lds_only();
        cur ^= 1;
    }

    // ctx store bf16, layout (H,B,S,dk)
    #pragma unroll
    for (int n = 0; n < 4; ++n) {
        const int d = n*16 + (l & 15);
        #pragma unroll
        for (int r = 0; r < 4; ++r) {
            const int q = q0 + w*16 + (l>>4)*4 + r;
            ctxb[(((size_t)h*BB + b)*SS + q)*DKK + d] = f2bf(cacc[n][r]);
        }
    }
}

// ---------------------------------------------------------------------------
// Out-proj GEMM + bias + residual: y(N,D) f32 = ctx(N,D)bf16 @ wo^T + bo + query
// ---------------------------------------------------------------------------
__global__ __launch_bounds__(256)
void k_gemmo(const unsigned short* __restrict__ X, const unsigned short* __restrict__ W,
             const float* __restrict__ bias, const float* __restrict__ resid,
             float* __restrict__ outf)
{
    __shared__ __align__(16) unsigned short Als[128*32];
    __shared__ __align__(16) unsigned short Bls[128*32];
    const int row0 = blockIdx.x * 128;
    const int col0 = blockIdx.y * 128;
    const int t = threadIdx.x;
    const int w = t >> 6, l = t & 63;
    const int wr = w >> 1, wc = w & 1;

    f32x4 acc[4][4];
    #pragma unroll
    for (int m=0;m<4;++m)
        #pragma unroll
        for (int n=0;n<4;++n) acc[m][n] = (f32x4){0.f,0.f,0.f,0.f};

    const int srow  = l >> 2;
    const int skoff = (l & 3) * 8;

    for (int kt = 0; kt < DD; kt += 32) {
        #pragma unroll
        for (int i=0;i<2;++i) {
            const unsigned short* ga = X + (size_t)(row0 + w*32 + i*16 + srow)*DD + kt + skoff;
            const unsigned short* gb = W + (size_t)(col0 + w*32 + i*16 + srow)*DD + kt + skoff;
            __builtin_amdgcn_global_load_lds((glb_u32*)ga, (lds_u32*)&Als[(w*2+i)*512], 16, 0, 0);
            __builtin_amdgcn_global_load_lds((glb_u32*)gb, (lds_u32*)&Bls[(w*2+i)*512], 16, 0, 0);
        }
        __syncthreads();
        bf16x8 af[4], bfr[4];
        #pragma unroll
        for (int m=0;m<4;++m)
            af[m] = *reinterpret_cast<const bf16x8*>(&Als[(wr*64 + m*16 + (l&15))*32 + (l>>4)*8]);
        #pragma unroll
        for (int n=0;n<4;++n)
            bfr[n] = *reinterpret_cast<const bf16x8*>(&Bls[(wc*64 + n*16 + (l&15))*32 + (l>>4)*8]);
        __builtin_amdgcn_s_setprio(1);
        #pragma unroll
        for (int m=0;m<4;++m)
            #pragma unroll
            for (int n=0;n<4;++n)
                acc[m][n] = __builtin_amdgcn_mfma_f32_16x16x32_bf16(af[m], bfr[n], acc[m][n], 0, 0, 0);
        __builtin_amdgcn_s_setprio(0);
        __syncthreads();
    }

    #pragma unroll
    for (int m=0;m<4;++m){
        const int grow_base = row0 + wr*64 + m*16 + ((l>>4)<<2);
        #pragma unroll
        for (int n=0;n<4;++n){
            const int col = col0 + wc*64 + n*16 + (l&15);
            const float bc = bias[col];
            #pragma unroll
            for (int r=0;r<4;++r){
                const int row = grow_base + r;
                outf[(size_t)row*DD + col] = acc[m][n][r] + bc + resid[(size_t)row*DD + col];
            }
        }
    }
}

// ---------------------------------------------------------------------------
// LayerNorm over last dim (1024), one block per row.
// ---------------------------------------------------------------------------
__global__ __launch_bounds__(256)
void k_ln(const float* __restrict__ y, const float* __restrict__ g,
          const float* __restrict__ be, float* __restrict__ out)
{
    const int row = blockIdx.x;
    const int t = threadIdx.x;
    float4 v = *reinterpret_cast<const float4*>(&y[(size_t)row*DD + t*4]);
    float s  = v.x + v.y + v.z + v.w;
    float ss = v.x*v.x + v.y*v.y + v.z*v.z + v.w*v.w;
    #pragma unroll
    for (int off = 32; off > 0; off >>= 1) {
        s  += __shfl_xor(s,  off, 64);
        ss += __shfl_xor(ss, off, 64);
    }
    __shared__ float red[8];
    const int lane = t & 63, wid = t >> 6;
    if (lane == 0) { red[wid] = s; red[4+wid] = ss; }
    __syncthreads();
    const float S1 = red[0]+red[1]+red[2]+red[3];
    const float S2 = red[4]+red[5]+red[6]+red[7];
    const float mu  = S1 * (1.0f/DD);
    const float var = fmaxf(S2 * (1.0f/DD) - mu*mu, 0.0f);
    const float rstd = rsqrtf(var + LN_EPS);
    float4 gv = *reinterpret_cast<const float4*>(&g[t*4]);
    float4 bv = *reinterpret_cast<const float4*>(&be[t*4]);
    float4 o;
    o.x = (v.x - mu)*rstd*gv.x + bv.x;
    o.y = (v.y - mu)*rstd*gv.y + bv.y;
    o.z = (v.z - mu)*rstd*gv.z + bv.z;
    o.w = (v.w - mu)*rstd*gv.w + bv.w;
    *reinterpret_cast<float4*>(&out[(size_t)row*DD + t*4]) = o;
}

// ---------------------------------------------------------------------------
extern "C" void kernel_launch(void* const* d_in, const int* in_sizes, int n_in,
                              void* d_out, int out_size, void* d_ws, size_t ws_size,
                              hipStream_t stream) {
    const float* query = (const float*)d_in[0];
    const float* key   = (const float*)d_in[1];
    const float* value = (const float*)d_in[2];
    const float* wq = (const float*)d_in[3];
    const float* bq = (const float*)d_in[4];
    const float* wk = (const float*)d_in[5];
    const float* bk = (const float*)d_in[6];
    const float* wv = (const float*)d_in[7];
    const float* bv = (const float*)d_in[8];
    const float* wo = (const float*)d_in[9];
    const float* bo = (const float*)d_in[10];
    // d_in[11] temporal_bias: constant along softmax axis -> softmax-invariant
    const float* at = (const float*)d_in[12];
    const float* g  = (const float*)d_in[13];
    const float* be = (const float*)d_in[14];

    float* out_ln = (float*)d_out;
    float* attn   = (float*)d_out + (size_t)NN*DD;

    char* wsb = (char*)d_ws;
    unsigned short* xq   = (unsigned short*)(wsb);                    // 24 MB: xq,xk,xv
    unsigned short* Qb   = (unsigned short*)(wsb + ((size_t)24<<20)); // 8 MB
    unsigned short* Kb   = (unsigned short*)(wsb + ((size_t)32<<20)); // 8 MB
    unsigned short* Vtb  = (unsigned short*)(wsb + ((size_t)40<<20)); // 8 MB (B,H,dk,S)
    unsigned short* ctxb = (unsigned short*)(wsb + ((size_t)48<<20)); // 8 MB
    unsigned short* wqb  = (unsigned short*)(wsb + ((size_t)56<<20)); // 8 MB: wq,wk,wv,wo
    float*          y    = (float*)(wsb);                             // 16 MB, over dead xq/xk

    k_cvt_all<<<8192, 256, 0, stream>>>(query, key, value, wq, wk, wv, wo, xq, wqb);

    k_gemmqkv<<<dim3(32, 8, 3), 256, 0, stream>>>(xq, wqb, bq, bk, bv, Qb);

    k_attn<<<dim3(512), 512, 0, stream>>>(Qb, Kb, Vtb, at, attn, ctxb);

    k_gemmo<<<dim3(32, 8), 256, 0, stream>>>(ctxb, wqb + (size_t)3*DD*DD, bo, query, y);

    k_ln<<<NN, 256, 0, stream>>>(y, g, be, out_ln);
}